// Round 5
// baseline (362.160 us; speedup 1.0000x reference)
//
#include <hip/hip_runtime.h>
#include <hip/hip_bf16.h>
#include <stdint.h>

// Problem constants: N=16384, K=2048, D=512
#define NN 16384
#define KK 2048
#define DD 512

typedef __bf16 bf16x8 __attribute__((ext_vector_type(8)));
typedef float f32x4 __attribute__((ext_vector_type(4)));
typedef unsigned short ushort_t;
typedef ushort_t us8 __attribute__((ext_vector_type(8)));

#define AS1(p) ((const __attribute__((address_space(1))) void*)(p))
#define AS3(p) ((__attribute__((address_space(3))) void*)(p))
#define FENCE() asm volatile("" ::: "memory")
#define SBAR()  do { FENCE(); __builtin_amdgcn_s_barrier(); FENCE(); } while (0)

__device__ inline ushort_t f2bf(float f) {
  uint32_t u = __float_as_uint(f);
  u += 0x7fffu + ((u >> 16) & 1u);   // RNE
  return (ushort_t)(u >> 16);
}

// Packed fragment-major images (verified passing, rounds 3-4):
// image = 128 rows x 32 k = 8KB; elem(row=m*16+r, k=slot*8+j) -> m*512+slot*128+r*8+j
// -> lane-linear ds_read_b128 (2 lanes/bank, conflict-free), linear 8KB staging.

// ---- Kernel 1: x -> packed bf16 images + x_sq[n] ----
__global__ __launch_bounds__(256) void prep_x(const float* __restrict__ x,
                                              ushort_t* __restrict__ xb,
                                              float* __restrict__ x_sq) {
  const int wave = threadIdx.x >> 6;
  const int lane = threadIdx.x & 63;
  const int row = blockIdx.x * 4 + wave;
  const float* xr = x + (size_t)row * DD + lane * 8;
  float4 v0 = *reinterpret_cast<const float4*>(xr);
  float4 v1 = *reinterpret_cast<const float4*>(xr + 4);
  float s = v0.x*v0.x + v0.y*v0.y + v0.z*v0.z + v0.w*v0.w
          + v1.x*v1.x + v1.y*v1.y + v1.z*v1.z + v1.w*v1.w;
  us8 o;
  o[0]=f2bf(v0.x); o[1]=f2bf(v0.y); o[2]=f2bf(v0.z); o[3]=f2bf(v0.w);
  o[4]=f2bf(v1.x); o[5]=f2bf(v1.y); o[6]=f2bf(v1.z); o[7]=f2bf(v1.w);

  const int br = row >> 7, m = (row >> 4) & 7, r = row & 15;
  const int kt = lane >> 2, slot = lane & 3;
  size_t off = ((size_t)(br * 16 + kt)) * 4096 + m * 512 + slot * 128 + r * 8;
  *reinterpret_cast<us8*>(xb + off) = o;

  #pragma unroll
  for (int offs = 32; offs; offs >>= 1) s += __shfl_xor(s, offs, 64);
  if (lane == 0) x_sq[row] = s;
}

// ---- Kernel 2: mu -> packed bf16 images + per-k constants ----
__global__ __launch_bounds__(256) void prep_mu(const float* __restrict__ mu,
                                               const float* __restrict__ sd,
                                               ushort_t* __restrict__ mub,
                                               float* __restrict__ inv_denom,
                                               float* __restrict__ beta) {
  const int wave = threadIdx.x >> 6;
  const int lane = threadIdx.x & 63;
  const int row = blockIdx.x * 4 + wave;
  const float* mr = mu + (size_t)row * DD + lane * 8;
  float4 v0 = *reinterpret_cast<const float4*>(mr);
  float4 v1 = *reinterpret_cast<const float4*>(mr + 4);
  float musq = v0.x*v0.x + v0.y*v0.y + v0.z*v0.z + v0.w*v0.w
             + v1.x*v1.x + v1.y*v1.y + v1.z*v1.z + v1.w*v1.w;
  us8 o;
  o[0]=f2bf(v0.x); o[1]=f2bf(v0.y); o[2]=f2bf(v0.z); o[3]=f2bf(v0.w);
  o[4]=f2bf(v1.x); o[5]=f2bf(v1.y); o[6]=f2bf(v1.z); o[7]=f2bf(v1.w);

  const int bc = row >> 7, m = (row >> 4) & 7, r = row & 15;
  const int kt = lane >> 2, slot = lane & 3;
  size_t off = ((size_t)(bc * 16 + kt)) * 4096 + m * 512 + slot * 128 + r * 8;
  *reinterpret_cast<us8*>(mub + off) = o;

  const float* sr = sd + (size_t)row * DD + lane * 8;
  float4 s0 = *reinterpret_cast<const float4*>(sr);
  float4 s1 = *reinterpret_cast<const float4*>(sr + 4);
  float ssum = s0.x + s0.y + s0.z + s0.w + s1.x + s1.y + s1.z + s1.w;
  float ssq  = s0.x*s0.x + s0.y*s0.y + s0.z*s0.z + s0.w*s0.w
             + s1.x*s1.x + s1.y*s1.y + s1.z*s1.z + s1.w*s1.w;
  #pragma unroll
  for (int offs = 32; offs; offs >>= 1) {
    musq += __shfl_xor(musq, offs, 64);
    ssum += __shfl_xor(ssum, offs, 64);
    ssq  += __shfl_xor(ssq,  offs, 64);
  }
  if (lane == 0) {
    float idn = 1.0f / (2.0f * ssq + 1e-8f);
    inv_denom[row] = idn;
    beta[row] = musq * idn + logf(ssum) + 0.91893853320467274f; // + 0.5*log(2pi)
  }
}

// ---- Kernel 3 (DIAGNOSTIC REP=2): identical R4 structure, body executed
//      twice so the dispatch becomes top-5 visible in rocprof and
//      dur_us - baseline gives the GEMM time directly. Output writes are
//      idempotent; barrier between reps prevents LDS write-before-read.
__global__ __launch_bounds__(256, 3) void gemm_eval(const ushort_t* __restrict__ xb,
                                                    const ushort_t* __restrict__ mub,
                                                    const float* __restrict__ x_sq,
                                                    const float* __restrict__ inv_denom,
                                                    const float* __restrict__ beta,
                                                    float* __restrict__ out) {
  __shared__ __align__(16) ushort_t lds[3][8192];   // 48 KiB -> 3 blocks/CU

  const int t0 = threadIdx.x;
  const int lane = t0 & 63;
  const int w = t0 >> 6;
  const int wrow = w >> 1;
  const int wcol = w & 1;

  const int bid = blockIdx.x;
  const int swz = (bid & 7) * 256 + (bid >> 3);   // bijective, 2048 % 8 == 0
  const int bm = swz >> 4, bn = swz & 15;

  const ushort_t* Aimg = xb  + (size_t)(bm * 16) * 4096;
  const ushort_t* Bimg = mub + (size_t)(bn * 16) * 4096;

#define ISSUE(kt_) do {                                                                  \
    const int b_ = (kt_) % 3;                                                            \
    const ushort_t* a_ = Aimg + (size_t)(kt_) * 4096;                                    \
    const ushort_t* bsrc_ = Bimg + (size_t)(kt_) * 4096;                                 \
    __builtin_amdgcn_global_load_lds(AS1(a_ + t0 * 8),                                   \
                                     AS3(&lds[b_][0] + t0 * 8), 16, 0, 0);               \
    __builtin_amdgcn_global_load_lds(AS1(a_ + (t0 + 256) * 8),                           \
                                     AS3(&lds[b_][0] + (t0 + 256) * 8), 16, 0, 0);       \
    __builtin_amdgcn_global_load_lds(AS1(bsrc_ + t0 * 8),                                \
                                     AS3(&lds[b_][4096] + t0 * 8), 16, 0, 0);            \
    __builtin_amdgcn_global_load_lds(AS1(bsrc_ + (t0 + 256) * 8),                        \
                                     AS3(&lds[b_][4096] + (t0 + 256) * 8), 16, 0, 0);    \
  } while (0)

#define TILE(t_, doIssue_, WAITASM) do {                                                 \
    const ushort_t* Ab_ = &lds[(t_) % 3][0];                                             \
    const ushort_t* Bb_ = &lds[(t_) % 3][4096];                                          \
    bf16x8 af_[4], bf_[4];                                                               \
    _Pragma("unroll") for (int m = 0; m < 4; ++m)                                        \
      af_[m] = *reinterpret_cast<const bf16x8*>(Ab_ + (wrow * 4 + m) * 512 + lane * 8);  \
    _Pragma("unroll") for (int c = 0; c < 4; ++c)                                        \
      bf_[c] = *reinterpret_cast<const bf16x8*>(Bb_ + (wcol * 4 + c) * 512 + lane * 8);  \
    if (doIssue_) ISSUE((t_) + 2);                                                       \
    __builtin_amdgcn_s_setprio(1);                                                       \
    _Pragma("unroll") for (int m = 0; m < 4; ++m)                                        \
      _Pragma("unroll") for (int c = 0; c < 4; ++c)                                      \
        acc[m][c] = __builtin_amdgcn_mfma_f32_16x16x32_bf16(af_[m], bf_[c],              \
                                                            acc[m][c], 0, 0, 0);         \
    __builtin_amdgcn_s_setprio(0);                                                       \
    WAITASM;                                                                             \
    SBAR();                                                                              \
  } while (0)

  for (int rep = 0; rep < 2; ++rep) {
    f32x4 acc[4][4];
    #pragma unroll
    for (int m = 0; m < 4; ++m)
      #pragma unroll
      for (int c = 0; c < 4; ++c)
        acc[m][c] = (f32x4){0.f, 0.f, 0.f, 0.f};

    if (rep) SBAR();   // all waves past rep0's LDS reads before re-staging
    ISSUE(0); ISSUE(1);
    asm volatile("s_waitcnt vmcnt(4)" ::: "memory");
    SBAR();

    #pragma unroll
    for (int t = 0; t < 14; ++t)
      TILE(t, 1, asm volatile("s_waitcnt vmcnt(4)" ::: "memory"));
    TILE(14, 0, asm volatile("s_waitcnt vmcnt(0)" ::: "memory"));
    {  // tile 15
      const ushort_t* Ab_ = &lds[15 % 3][0];
      const ushort_t* Bb_ = &lds[15 % 3][4096];
      bf16x8 af_[4], bf_[4];
      #pragma unroll
      for (int m = 0; m < 4; ++m)
        af_[m] = *reinterpret_cast<const bf16x8*>(Ab_ + (wrow * 4 + m) * 512 + lane * 8);
      #pragma unroll
      for (int c = 0; c < 4; ++c)
        bf_[c] = *reinterpret_cast<const bf16x8*>(Bb_ + (wcol * 4 + c) * 512 + lane * 8);
      #pragma unroll
      for (int m = 0; m < 4; ++m)
        #pragma unroll
        for (int c = 0; c < 4; ++c)
          acc[m][c] = __builtin_amdgcn_mfma_f32_16x16x32_bf16(af_[m], bf_[c],
                                                              acc[m][c], 0, 0, 0);
    }

    // epilogue (idempotent across reps)
    const int rl = lane & 15, rh = lane >> 4;
    const int colbase = bn * 128 + wcol * 64;
    float inv[4], bet[4];
    #pragma unroll
    for (int c = 0; c < 4; ++c) {
      inv[c] = inv_denom[colbase + c * 16 + rl];
      bet[c] = beta[colbase + c * 16 + rl];
    }
    #pragma unroll
    for (int m = 0; m < 4; ++m) {
      const int nb = bm * 128 + wrow * 64 + m * 16 + rh * 4;
      #pragma unroll
      for (int reg = 0; reg < 4; ++reg) {
        const int n = nb + reg;
        const float xs = x_sq[n];
        float* op = out + (size_t)n * KK + colbase;
        #pragma unroll
        for (int c = 0; c < 4; ++c)
          op[c * 16 + rl] = (2.0f * acc[m][c][reg] - xs) * inv[c] - bet[c];
      }
    }
    FENCE();
  }
#undef TILE
#undef ISSUE
}

extern "C" void kernel_launch(void* const* d_in, const int* in_sizes, int n_in,
                              void* d_out, int out_size, void* d_ws, size_t ws_size,
                              hipStream_t stream) {
  const float* x   = (const float*)d_in[0];
  const float* mu  = (const float*)d_in[1];
  const float* sd  = (const float*)d_in[2];
  float* out = (float*)d_out;

  char* ws = (char*)d_ws;
  ushort_t* xb        = (ushort_t*)(ws);                    // N*D*2 = 16777216 B
  ushort_t* mub       = (ushort_t*)(ws + 16777216);         // K*D*2 =  2097152 B
  float*    x_sq      = (float*)(ws + 18874368);            // N*4
  float*    inv_denom = (float*)(ws + 18939904);            // K*4
  float*    beta      = (float*)(ws + 18948096);            // K*4

  prep_mu<<<KK / 4, 256, 0, stream>>>(mu, sd, mub, inv_denom, beta);
  prep_x<<<NN / 4, 256, 0, stream>>>(x, xb, x_sq);
  gemm_eval<<<(NN / 128) * (KK / 128), 256, 0, stream>>>(xb, mub, x_sq, inv_denom, beta, out);
}